// Round 1
// baseline (1794.128 us; speedup 1.0000x reference)
//
#include <hip/hip_runtime.h>
#include <hip/hip_bf16.h>

#define NTOK 16384
#define DIM  1024
#define NEXP 8
#define DFF  4096
#define PADR 128
#define MAXROWS (2*NTOK + NEXP*PADR)   /* 33792 */

typedef __bf16 bf16x8 __attribute__((ext_vector_type(8)));
typedef float  f32x4  __attribute__((ext_vector_type(4)));

static __device__ __forceinline__ unsigned short f2bf(float f) {
    __hip_bfloat16 h = __float2bfloat16(f);
    return *reinterpret_cast<unsigned short*>(&h);
}

// ---------------- small setup kernels ----------------

__global__ void zero_init(int* pair_token, int* counts, int* cursors, int* active,
                          float* cbuf, const float* __restrict__ b2) {
    int i = blockIdx.x * 256 + threadIdx.x;
    if (i < MAXROWS) pair_token[i] = -1;
    if (i < NEXP) { counts[i] = 0; cursors[i] = 0; }
    if (i < 2*NEXP) active[i] = 0;
    if (i < NEXP*DIM) cbuf[i] = b2[i];   // c starts at b2, chunks atomicAdd onto it
}

__global__ void cvt_x(const float* __restrict__ x, unsigned short* __restrict__ xb) {
    size_t i = (size_t)blockIdx.x * 256 + threadIdx.x;
    if (i < (size_t)NTOK * DIM) xb[i] = f2bf(x[i]);
}

// in [B][R][C] f32  ->  out [B][C][R] bf16
__global__ void transpose_cvt(const float* __restrict__ in, unsigned short* __restrict__ out,
                              int R, int C) {
    __shared__ float tile[32][33];
    const float* ib = in + (size_t)blockIdx.z * R * C;
    unsigned short* ob = out + (size_t)blockIdx.z * R * C;
    int tx = threadIdx.x, ty = threadIdx.y;
    int c = blockIdx.x * 32 + tx;
    #pragma unroll
    for (int yy = 0; yy < 4; ++yy) {
        int r = blockIdx.y * 32 + ty + yy * 8;
        tile[ty + yy * 8][tx] = ib[(size_t)r * C + c];
    }
    __syncthreads();
    int oc = blockIdx.y * 32 + tx;
    #pragma unroll
    for (int yy = 0; yy < 4; ++yy) {
        int orow = blockIdx.x * 32 + ty + yy * 8;
        ob[(size_t)orow * R + oc] = f2bf(tile[tx][ty + yy * 8]);
    }
}

// one wave per token: logits, softmax, top-2
__global__ void router(const float* __restrict__ x, const float* __restrict__ wg,
                       const float* __restrict__ bg, int* __restrict__ tk_idx,
                       float* __restrict__ tk_score, int* counts, int* active) {
    int wave = threadIdx.x >> 6;
    int lane = threadIdx.x & 63;
    int t = blockIdx.x * 4 + wave;

    float acc[NEXP];
    #pragma unroll
    for (int e = 0; e < NEXP; ++e) acc[e] = 0.f;

    const float4* xr4 = reinterpret_cast<const float4*>(x + (size_t)t * DIM + lane * 16);
    const float* wr = wg + (size_t)lane * 16 * NEXP;
    #pragma unroll
    for (int jj = 0; jj < 4; ++jj) {
        float4 xv = xr4[jj];
        float xs[4] = {xv.x, xv.y, xv.z, xv.w};
        #pragma unroll
        for (int q = 0; q < 4; ++q) {
            const float* w = wr + (jj * 4 + q) * NEXP;
            #pragma unroll
            for (int e = 0; e < NEXP; ++e) acc[e] += xs[q] * w[e];
        }
    }
    #pragma unroll
    for (int e = 0; e < NEXP; ++e) {
        float v = acc[e];
        for (int off = 32; off; off >>= 1) v += __shfl_xor(v, off, 64);
        acc[e] = v;
    }
    if (lane == 0) {
        float l[NEXP];
        #pragma unroll
        for (int e = 0; e < NEXP; ++e) l[e] = acc[e] + bg[e];
        float m = l[0];
        #pragma unroll
        for (int e = 1; e < NEXP; ++e) m = fmaxf(m, l[e]);
        float ex[NEXP], s = 0.f;
        #pragma unroll
        for (int e = 0; e < NEXP; ++e) { ex[e] = expf(l[e] - m); s += ex[e]; }
        // top-1 (ties -> lowest index), then top-2
        int i1 = 0; float b1v = l[0];
        #pragma unroll
        for (int e = 1; e < NEXP; ++e) if (l[e] > b1v) { b1v = l[e]; i1 = e; }
        int i2 = -1; float b2v = -1e30f;
        #pragma unroll
        for (int e = 0; e < NEXP; ++e) if (e != i1 && l[e] > b2v) { b2v = l[e]; i2 = e; }
        float inv = 1.f / s;
        tk_idx[2 * t] = i1;  tk_idx[2 * t + 1] = i2;
        tk_score[2 * t] = ex[i1] * inv;  tk_score[2 * t + 1] = ex[i2] * inv;
        atomicAdd(&counts[i1], 1);
        atomicAdd(&counts[i2], 1);
        active[i1] = 1;           // slot 0
        active[NEXP + i2] = 1;    // slot 1
    }
}

// c[e] += relu(b1[e]) @ W2[e]  (b2 pre-loaded by zero_init), f-chunked
__global__ void expert_const(const float* __restrict__ b1, const float* __restrict__ W2,
                             float* __restrict__ cbuf) {
    int e = blockIdx.y;
    int d = blockIdx.x * 256 + threadIdx.x;
    int f0 = blockIdx.z * 512;
    const float* w = W2 + (size_t)e * DFF * DIM + (size_t)f0 * DIM + d;
    const float* b = b1 + e * DFF + f0;
    float s0 = 0.f, s1 = 0.f, s2 = 0.f, s3 = 0.f;
    for (int f = 0; f < 512; f += 4) {
        s0 += fmaxf(b[f + 0], 0.f) * w[(size_t)(f + 0) * DIM];
        s1 += fmaxf(b[f + 1], 0.f) * w[(size_t)(f + 1) * DIM];
        s2 += fmaxf(b[f + 2], 0.f) * w[(size_t)(f + 2) * DIM];
        s3 += fmaxf(b[f + 3], 0.f) * w[(size_t)(f + 3) * DIM];
    }
    atomicAdd(&cbuf[e * DIM + d], s0 + s1 + s2 + s3);
}

__global__ void prefix_off(const int* __restrict__ counts, int* __restrict__ po) {
    if (threadIdx.x == 0 && blockIdx.x == 0) {
        int acc = 0;
        for (int e = 0; e < NEXP; ++e) {
            po[e] = acc;
            acc += ((counts[e] + PADR - 1) / PADR) * PADR;
        }
        po[NEXP] = acc;
    }
}

__global__ void scatter_pairs(const int* __restrict__ tk_idx, const float* __restrict__ tk_score,
                              const int* __restrict__ po, int* cursors,
                              int* pair_token, float* pair_score) {
    int i = blockIdx.x * 256 + threadIdx.x;   // < 2N
    int t = i >> 1, slot = i & 1;
    int e = tk_idx[2 * t + slot];
    int pos = atomicAdd(&cursors[e], 1);
    int r = po[e] + pos;
    pair_token[r] = t;
    pair_score[r] = tk_score[2 * t + slot];
}

__global__ void combine_C(const int* __restrict__ active, const float* __restrict__ cbuf,
                          float* __restrict__ C2) {
    int i = blockIdx.x * 256 + threadIdx.x;   // < 2048
    int slot = i >> 10, d = i & 1023;
    float s = 0.f;
    #pragma unroll
    for (int e = 0; e < NEXP; ++e)
        if (active[slot * NEXP + e]) s += cbuf[e * DIM + d];
    C2[i] = s;
}

__global__ void init_out(const float* __restrict__ tk_score, const float* __restrict__ C2,
                         float* __restrict__ out) {
    size_t i = (size_t)blockIdx.x * 256 + threadIdx.x;   // < N*DIM
    int t = (int)(i >> 10);
    int d = (int)(i & 1023);
    out[i] = tk_score[2 * t] * C2[d] + tk_score[2 * t + 1] * C2[DIM + d];
}

// ---------------- GEMM 1: H = relu(X@W1+b1)-relu(b1), gathered rows ----------------
// grid (DFF/128, MAXROWS/128), block 256. W1T layout [E][DFF][DIM] bf16.

__global__ __launch_bounds__(256, 2) void gemm1(
    const unsigned short* __restrict__ xb, const unsigned short* __restrict__ w1t,
    const float* __restrict__ b1, const int* __restrict__ pair_token,
    const int* __restrict__ po, unsigned short* __restrict__ H) {
    __shared__ unsigned short As[128 * 32];
    __shared__ unsigned short Bs[128 * 32];
    __shared__ int ptok[128];

    int rstart = blockIdx.y * 128;
    int total = po[NEXP];
    if (rstart >= total) return;
    int e = 0;
    #pragma unroll
    for (int i = 0; i < NEXP - 1; ++i) if (rstart >= po[i + 1]) e = i + 1;

    int tid = threadIdx.x;
    if (tid < 128) {
        int tkn = pair_token[rstart + tid];
        ptok[tid] = tkn < 0 ? 0 : tkn;
    }
    __syncthreads();

    int wave = tid >> 6, lane = tid & 63;
    int wr = (wave >> 1) * 64, wc = (wave & 1) * 64;
    int lm = lane & 15, k8 = (lane >> 4) * 8;
    int arow = tid >> 2;
    int ac8 = (tid & 3) * 8;

    f32x4 acc[4][4];
    #pragma unroll
    for (int i = 0; i < 4; ++i)
        #pragma unroll
        for (int j = 0; j < 4; ++j) acc[i][j] = (f32x4){0.f, 0.f, 0.f, 0.f};

    const unsigned short* bbase =
        w1t + (size_t)e * DFF * DIM + (size_t)(blockIdx.x * 128) * DIM;

    for (int kt = 0; kt < DIM / 32; ++kt) {
        int k0 = kt * 32;
        if (kt) __syncthreads();
        #pragma unroll
        for (int p = 0; p < 2; ++p) {
            int r = p * 64 + arow;
            uint4 va = *reinterpret_cast<const uint4*>(xb + (size_t)ptok[r] * DIM + k0 + ac8);
            *reinterpret_cast<uint4*>(&As[r * 32 + ac8]) = va;
            uint4 vb = *reinterpret_cast<const uint4*>(bbase + (size_t)r * DIM + k0 + ac8);
            *reinterpret_cast<uint4*>(&Bs[r * 32 + ac8]) = vb;
        }
        __syncthreads();
        bf16x8 af[4], bfr[4];
        #pragma unroll
        for (int i = 0; i < 4; ++i)
            af[i] = *reinterpret_cast<const bf16x8*>(&As[(wr + i * 16 + lm) * 32 + k8]);
        #pragma unroll
        for (int j = 0; j < 4; ++j)
            bfr[j] = *reinterpret_cast<const bf16x8*>(&Bs[(wc + j * 16 + lm) * 32 + k8]);
        #pragma unroll
        for (int i = 0; i < 4; ++i)
            #pragma unroll
            for (int j = 0; j < 4; ++j)
                acc[i][j] = __builtin_amdgcn_mfma_f32_16x16x32_bf16(af[i], bfr[j], acc[i][j], 0, 0, 0);
    }

    int ctile = blockIdx.x * 128;
    #pragma unroll
    for (int j = 0; j < 4; ++j) {
        int n = ctile + wc + j * 16 + lm;
        float bv = b1[e * DFF + n];
        float rb = fmaxf(bv, 0.f);
        #pragma unroll
        for (int i = 0; i < 4; ++i) {
            int rbase = wr + i * 16 + ((lane >> 4) << 2);
            #pragma unroll
            for (int r = 0; r < 4; ++r) {
                float h = fmaxf(acc[i][j][r] + bv, 0.f) - rb;
                H[(size_t)(rstart + rbase + r) * DFF + n] = f2bf(h);
            }
        }
    }
}

// ---------------- GEMM 2: out[token] += score * (H @ W2) ----------------
// grid (DIM/128, MAXROWS/128), block 256. W2T layout [E][DIM][DFF] bf16.

__global__ __launch_bounds__(256, 2) void gemm2(
    const unsigned short* __restrict__ H, const unsigned short* __restrict__ w2t,
    const int* __restrict__ pair_token, const float* __restrict__ pair_score,
    const int* __restrict__ po, float* __restrict__ out) {
    __shared__ unsigned short As[128 * 32];
    __shared__ unsigned short Bs[128 * 32];
    __shared__ int ptok[128];
    __shared__ float pscr[128];

    int rstart = blockIdx.y * 128;
    int total = po[NEXP];
    if (rstart >= total) return;
    int e = 0;
    #pragma unroll
    for (int i = 0; i < NEXP - 1; ++i) if (rstart >= po[i + 1]) e = i + 1;

    int tid = threadIdx.x;
    if (tid < 128) {
        ptok[tid] = pair_token[rstart + tid];
        pscr[tid] = pair_score[rstart + tid];
    }
    __syncthreads();

    int wave = tid >> 6, lane = tid & 63;
    int wr = (wave >> 1) * 64, wc = (wave & 1) * 64;
    int lm = lane & 15, k8 = (lane >> 4) * 8;
    int arow = tid >> 2;
    int ac8 = (tid & 3) * 8;

    f32x4 acc[4][4];
    #pragma unroll
    for (int i = 0; i < 4; ++i)
        #pragma unroll
        for (int j = 0; j < 4; ++j) acc[i][j] = (f32x4){0.f, 0.f, 0.f, 0.f};

    const unsigned short* bbase =
        w2t + (size_t)e * DIM * DFF + (size_t)(blockIdx.x * 128) * DFF;
    const unsigned short* abase = H + (size_t)rstart * DFF;

    for (int kt = 0; kt < DFF / 32; ++kt) {
        int k0 = kt * 32;
        if (kt) __syncthreads();
        #pragma unroll
        for (int p = 0; p < 2; ++p) {
            int r = p * 64 + arow;
            uint4 va = *reinterpret_cast<const uint4*>(abase + (size_t)r * DFF + k0 + ac8);
            *reinterpret_cast<uint4*>(&As[r * 32 + ac8]) = va;
            uint4 vb = *reinterpret_cast<const uint4*>(bbase + (size_t)r * DFF + k0 + ac8);
            *reinterpret_cast<uint4*>(&Bs[r * 32 + ac8]) = vb;
        }
        __syncthreads();
        bf16x8 af[4], bfr[4];
        #pragma unroll
        for (int i = 0; i < 4; ++i)
            af[i] = *reinterpret_cast<const bf16x8*>(&As[(wr + i * 16 + lm) * 32 + k8]);
        #pragma unroll
        for (int j = 0; j < 4; ++j)
            bfr[j] = *reinterpret_cast<const bf16x8*>(&Bs[(wc + j * 16 + lm) * 32 + k8]);
        #pragma unroll
        for (int i = 0; i < 4; ++i)
            #pragma unroll
            for (int j = 0; j < 4; ++j)
                acc[i][j] = __builtin_amdgcn_mfma_f32_16x16x32_bf16(af[i], bfr[j], acc[i][j], 0, 0, 0);
    }

    int ctile = blockIdx.x * 128;
    #pragma unroll
    for (int j = 0; j < 4; ++j) {
        int n = ctile + wc + j * 16 + lm;
        #pragma unroll
        for (int i = 0; i < 4; ++i) {
            int rbase = wr + i * 16 + ((lane >> 4) << 2);
            #pragma unroll
            for (int r = 0; r < 4; ++r) {
                int rl = rbase + r;
                int tkn = ptok[rl];
                if (tkn >= 0)
                    atomicAdd(out + (size_t)tkn * DIM + n, pscr[rl] * acc[i][j][r]);
            }
        }
    }
}

// ---------------- launch ----------------

extern "C" void kernel_launch(void* const* d_in, const int* in_sizes, int n_in,
                              void* d_out, int out_size, void* d_ws, size_t ws_size,
                              hipStream_t stream) {
    const float* x   = (const float*)d_in[0];
    const float* w_g = (const float*)d_in[1];
    const float* b_g = (const float*)d_in[2];
    const float* W1  = (const float*)d_in[3];
    const float* b1  = (const float*)d_in[4];
    const float* W2  = (const float*)d_in[5];
    const float* b2  = (const float*)d_in[6];
    float* out = (float*)d_out;

    char* p = (char*)d_ws;
    auto alloc = [&](size_t bytes) {
        void* r = (void*)p;
        p += (bytes + 255) & ~(size_t)255;
        return r;
    };
    unsigned short* xb  = (unsigned short*)alloc((size_t)NTOK * DIM * 2);
    unsigned short* w1t = (unsigned short*)alloc((size_t)NEXP * DFF * DIM * 2);
    unsigned short* w2t = (unsigned short*)alloc((size_t)NEXP * DIM * DFF * 2);
    unsigned short* H   = (unsigned short*)alloc((size_t)MAXROWS * DFF * 2);
    int*   pair_token = (int*)alloc(MAXROWS * 4);
    float* pair_score = (float*)alloc(MAXROWS * 4);
    int*   tk_idx     = (int*)alloc(NTOK * 2 * 4);
    float* tk_score   = (float*)alloc(NTOK * 2 * 4);
    int*   counts     = (int*)alloc(NEXP * 4);
    int*   cursors    = (int*)alloc(NEXP * 4);
    int*   active     = (int*)alloc(2 * NEXP * 4);
    int*   po         = (int*)alloc((NEXP + 1) * 4);
    float* cbuf       = (float*)alloc(NEXP * DIM * 4);
    float* C2         = (float*)alloc(2 * DIM * 4);

    zero_init<<<(MAXROWS + 255) / 256, 256, 0, stream>>>(pair_token, counts, cursors, active, cbuf, b2);
    cvt_x<<<(NTOK * DIM + 255) / 256, 256, 0, stream>>>(x, xb);
    transpose_cvt<<<dim3(DFF / 32, DIM / 32, NEXP), dim3(32, 8), 0, stream>>>(W1, w1t, DIM, DFF);
    transpose_cvt<<<dim3(DIM / 32, DFF / 32, NEXP), dim3(32, 8), 0, stream>>>(W2, w2t, DFF, DIM);
    router<<<NTOK / 4, 256, 0, stream>>>(x, w_g, b_g, tk_idx, tk_score, counts, active);
    expert_const<<<dim3(DIM / 256, NEXP, DFF / 512), 256, 0, stream>>>(b1, W2, cbuf);
    prefix_off<<<1, 64, 0, stream>>>(counts, po);
    scatter_pairs<<<(2 * NTOK) / 256, 256, 0, stream>>>(tk_idx, tk_score, po, cursors, pair_token, pair_score);
    combine_C<<<(2 * DIM) / 256, 256, 0, stream>>>(active, cbuf, C2);
    init_out<<<(NTOK * DIM) / 256, 256, 0, stream>>>(tk_score, C2, out);
    gemm1<<<dim3(DFF / 128, MAXROWS / 128), 256, 0, stream>>>(xb, w1t, b1, pair_token, po, H);
    gemm2<<<dim3(DIM / 128, MAXROWS / 128), 256, 0, stream>>>(H, w2t, pair_token, pair_score, po, out);
}

// Round 2
// 1745.462 us; speedup vs baseline: 1.0279x; 1.0279x over previous
//
#include <hip/hip_runtime.h>
#include <hip/hip_bf16.h>

#define NTOK 16384
#define DIM  1024
#define NEXP 8
#define DFF  4096
#define PADR 128
#define MAXROWS (2*NTOK + NEXP*PADR)   /* 33792 */

typedef __bf16 bf16x8 __attribute__((ext_vector_type(8)));
typedef float  f32x4  __attribute__((ext_vector_type(4)));

#define AS1(p) ((const __attribute__((address_space(1))) void*)(p))
#define AS3(p) ((__attribute__((address_space(3))) void*)(p))

static __device__ __forceinline__ unsigned short f2bf(float f) {
    __hip_bfloat16 h = __float2bfloat16(f);
    return *reinterpret_cast<unsigned short*>(&h);
}

// ---------------- small setup kernels ----------------

__global__ void zero_init(int* pair_token, int* counts, int* cursors, int* active,
                          float* cbuf, const float* __restrict__ b2) {
    int i = blockIdx.x * 256 + threadIdx.x;
    if (i < MAXROWS) pair_token[i] = -1;
    if (i < NEXP) { counts[i] = 0; cursors[i] = 0; }
    if (i < 2*NEXP) active[i] = 0;
    if (i < NEXP*DIM) cbuf[i] = b2[i];   // c starts at b2, chunks atomicAdd onto it
}

__global__ void cvt_x(const float* __restrict__ x, unsigned short* __restrict__ xb) {
    size_t i = (size_t)blockIdx.x * 256 + threadIdx.x;
    if (i < (size_t)NTOK * DIM) xb[i] = f2bf(x[i]);
}

// in [B][R][C] f32  ->  out [B][C][R] bf16
__global__ void transpose_cvt(const float* __restrict__ in, unsigned short* __restrict__ out,
                              int R, int C) {
    __shared__ float tile[32][33];
    const float* ib = in + (size_t)blockIdx.z * R * C;
    unsigned short* ob = out + (size_t)blockIdx.z * R * C;
    int tx = threadIdx.x, ty = threadIdx.y;
    int c = blockIdx.x * 32 + tx;
    #pragma unroll
    for (int yy = 0; yy < 4; ++yy) {
        int r = blockIdx.y * 32 + ty + yy * 8;
        tile[ty + yy * 8][tx] = ib[(size_t)r * C + c];
    }
    __syncthreads();
    int oc = blockIdx.y * 32 + tx;
    #pragma unroll
    for (int yy = 0; yy < 4; ++yy) {
        int orow = blockIdx.x * 32 + ty + yy * 8;
        ob[(size_t)orow * R + oc] = f2bf(tile[tx][ty + yy * 8]);
    }
}

// one wave per token: logits, softmax, top-2
__global__ void router(const float* __restrict__ x, const float* __restrict__ wg,
                       const float* __restrict__ bg, int* __restrict__ tk_idx,
                       float* __restrict__ tk_score, int* counts, int* active) {
    int wave = threadIdx.x >> 6;
    int lane = threadIdx.x & 63;
    int t = blockIdx.x * 4 + wave;

    float acc[NEXP];
    #pragma unroll
    for (int e = 0; e < NEXP; ++e) acc[e] = 0.f;

    const float4* xr4 = reinterpret_cast<const float4*>(x + (size_t)t * DIM + lane * 16);
    const float* wr = wg + (size_t)lane * 16 * NEXP;
    #pragma unroll
    for (int jj = 0; jj < 4; ++jj) {
        float4 xv = xr4[jj];
        float xs[4] = {xv.x, xv.y, xv.z, xv.w};
        #pragma unroll
        for (int q = 0; q < 4; ++q) {
            const float* w = wr + (jj * 4 + q) * NEXP;
            #pragma unroll
            for (int e = 0; e < NEXP; ++e) acc[e] += xs[q] * w[e];
        }
    }
    #pragma unroll
    for (int e = 0; e < NEXP; ++e) {
        float v = acc[e];
        for (int off = 32; off; off >>= 1) v += __shfl_xor(v, off, 64);
        acc[e] = v;
    }
    if (lane == 0) {
        float l[NEXP];
        #pragma unroll
        for (int e = 0; e < NEXP; ++e) l[e] = acc[e] + bg[e];
        float m = l[0];
        #pragma unroll
        for (int e = 1; e < NEXP; ++e) m = fmaxf(m, l[e]);
        float ex[NEXP], s = 0.f;
        #pragma unroll
        for (int e = 0; e < NEXP; ++e) { ex[e] = expf(l[e] - m); s += ex[e]; }
        // top-1 (ties -> lowest index), then top-2
        int i1 = 0; float b1v = l[0];
        #pragma unroll
        for (int e = 1; e < NEXP; ++e) if (l[e] > b1v) { b1v = l[e]; i1 = e; }
        int i2 = -1; float b2v = -1e30f;
        #pragma unroll
        for (int e = 0; e < NEXP; ++e) if (e != i1 && l[e] > b2v) { b2v = l[e]; i2 = e; }
        float inv = 1.f / s;
        tk_idx[2 * t] = i1;  tk_idx[2 * t + 1] = i2;
        tk_score[2 * t] = ex[i1] * inv;  tk_score[2 * t + 1] = ex[i2] * inv;
        atomicAdd(&counts[i1], 1);
        atomicAdd(&counts[i2], 1);
        active[i1] = 1;           // slot 0
        active[NEXP + i2] = 1;    // slot 1
    }
}

// c[e] += relu(b1[e]) @ W2[e]  (b2 pre-loaded by zero_init), f-chunked
__global__ void expert_const(const float* __restrict__ b1, const float* __restrict__ W2,
                             float* __restrict__ cbuf) {
    int e = blockIdx.y;
    int d = blockIdx.x * 256 + threadIdx.x;
    int f0 = blockIdx.z * 512;
    const float* w = W2 + (size_t)e * DFF * DIM + (size_t)f0 * DIM + d;
    const float* b = b1 + e * DFF + f0;
    float s0 = 0.f, s1 = 0.f, s2 = 0.f, s3 = 0.f;
    for (int f = 0; f < 512; f += 4) {
        s0 += fmaxf(b[f + 0], 0.f) * w[(size_t)(f + 0) * DIM];
        s1 += fmaxf(b[f + 1], 0.f) * w[(size_t)(f + 1) * DIM];
        s2 += fmaxf(b[f + 2], 0.f) * w[(size_t)(f + 2) * DIM];
        s3 += fmaxf(b[f + 3], 0.f) * w[(size_t)(f + 3) * DIM];
    }
    atomicAdd(&cbuf[e * DIM + d], s0 + s1 + s2 + s3);
}

__global__ void prefix_off(const int* __restrict__ counts, int* __restrict__ po) {
    if (threadIdx.x == 0 && blockIdx.x == 0) {
        int acc = 0;
        for (int e = 0; e < NEXP; ++e) {
            po[e] = acc;
            acc += ((counts[e] + PADR - 1) / PADR) * PADR;
        }
        po[NEXP] = acc;
    }
}

__global__ void scatter_pairs(const int* __restrict__ tk_idx, const float* __restrict__ tk_score,
                              const int* __restrict__ po, int* cursors,
                              int* pair_token, float* pair_score) {
    int i = blockIdx.x * 256 + threadIdx.x;   // < 2N
    int t = i >> 1, slot = i & 1;
    int e = tk_idx[2 * t + slot];
    int pos = atomicAdd(&cursors[e], 1);
    int r = po[e] + pos;
    pair_token[r] = t;
    pair_score[r] = tk_score[2 * t + slot];
}

__global__ void combine_C(const int* __restrict__ active, const float* __restrict__ cbuf,
                          float* __restrict__ C2) {
    int i = blockIdx.x * 256 + threadIdx.x;   // < 2048
    int slot = i >> 10, d = i & 1023;
    float s = 0.f;
    #pragma unroll
    for (int e = 0; e < NEXP; ++e)
        if (active[slot * NEXP + e]) s += cbuf[e * DIM + d];
    C2[i] = s;
}

__global__ void init_out(const float* __restrict__ tk_score, const float* __restrict__ C2,
                         float* __restrict__ out) {
    size_t i = (size_t)blockIdx.x * 256 + threadIdx.x;   // < N*DIM
    int t = (int)(i >> 10);
    int d = (int)(i & 1023);
    out[i] = tk_score[2 * t] * C2[d] + tk_score[2 * t + 1] * C2[DIM + d];
}

// ---------------- GEMM 1: H = relu(X@W1+b1)-relu(b1), gathered rows ----------------
// grid (DFF/128, MAXROWS/128), block 256. W1T layout [E][DFF][DIM] bf16.
// Staging via global_load_lds width=16; bank-conflict XOR swizzle applied on the
// GLOBAL side (LDS dest is forced to base+lane*16): chunk q_log = q ^ ((row>>1)&3).

__global__ __launch_bounds__(256, 2) void gemm1(
    const unsigned short* __restrict__ xb, const unsigned short* __restrict__ w1t,
    const float* __restrict__ b1, const int* __restrict__ pair_token,
    const int* __restrict__ po, unsigned short* __restrict__ H) {
    __shared__ unsigned short As[128 * 32];
    __shared__ unsigned short Bs[128 * 32];
    __shared__ int ptok[128];

    int rstart = blockIdx.y * 128;
    int total = po[NEXP];
    if (rstart >= total) return;
    int e = 0;
    #pragma unroll
    for (int i = 0; i < NEXP - 1; ++i) if (rstart >= po[i + 1]) e = i + 1;

    int tid = threadIdx.x;
    if (tid < 128) {
        int tkn = pair_token[rstart + tid];
        ptok[tid] = tkn < 0 ? 0 : tkn;
    }
    __syncthreads();

    int wave = tid >> 6, lane = tid & 63;
    int wr = (wave >> 1) * 64, wc = (wave & 1) * 64;
    int lm = lane & 15, kq = lane >> 4;

    // staging lane roles: 2 instrs/wave per operand, 16 rows each
    int rl = lane >> 2, q = lane & 3;
    int rA0 = wave * 32 + rl;        // rows [wave*32, wave*32+16)
    int rA1 = rA0 + 16;
    int q0 = q ^ ((rA0 >> 1) & 3);
    int q1 = q ^ ((rA1 >> 1) & 3);

    const unsigned short* bbase =
        w1t + (size_t)e * DFF * DIM + (size_t)(blockIdx.x * 128) * DIM;

    const unsigned short* gA0 = xb + (size_t)ptok[rA0] * DIM + q0 * 8;
    const unsigned short* gA1 = xb + (size_t)ptok[rA1] * DIM + q1 * 8;
    const unsigned short* gB0 = bbase + (size_t)rA0 * DIM + q0 * 8;
    const unsigned short* gB1 = bbase + (size_t)rA1 * DIM + q1 * 8;
    unsigned short* lA0 = &As[(wave * 32) * 32];
    unsigned short* lA1 = &As[(wave * 32 + 16) * 32];
    unsigned short* lB0 = &Bs[(wave * 32) * 32];
    unsigned short* lB1 = &Bs[(wave * 32 + 16) * 32];

    f32x4 acc[4][4];
    #pragma unroll
    for (int i = 0; i < 4; ++i)
        #pragma unroll
        for (int j = 0; j < 4; ++j) acc[i][j] = (f32x4){0.f, 0.f, 0.f, 0.f};

    for (int kt = 0; kt < DIM / 32; ++kt) {
        int k0 = kt * 32;
        if (kt) __syncthreads();
        __builtin_amdgcn_global_load_lds(AS1(gA0 + k0), AS3(lA0), 16, 0, 0);
        __builtin_amdgcn_global_load_lds(AS1(gA1 + k0), AS3(lA1), 16, 0, 0);
        __builtin_amdgcn_global_load_lds(AS1(gB0 + k0), AS3(lB0), 16, 0, 0);
        __builtin_amdgcn_global_load_lds(AS1(gB1 + k0), AS3(lB1), 16, 0, 0);
        __syncthreads();
        bf16x8 af[4], bfr[4];
        #pragma unroll
        for (int i = 0; i < 4; ++i) {
            int R = wr + i * 16 + lm;
            af[i] = *reinterpret_cast<const bf16x8*>(&As[R * 32 + ((kq ^ ((R >> 1) & 3)) << 3)]);
        }
        #pragma unroll
        for (int j = 0; j < 4; ++j) {
            int R = wc + j * 16 + lm;
            bfr[j] = *reinterpret_cast<const bf16x8*>(&Bs[R * 32 + ((kq ^ ((R >> 1) & 3)) << 3)]);
        }
        #pragma unroll
        for (int i = 0; i < 4; ++i)
            #pragma unroll
            for (int j = 0; j < 4; ++j)
                acc[i][j] = __builtin_amdgcn_mfma_f32_16x16x32_bf16(af[i], bfr[j], acc[i][j], 0, 0, 0);
    }

    int ctile = blockIdx.x * 128;
    #pragma unroll
    for (int j = 0; j < 4; ++j) {
        int n = ctile + wc + j * 16 + lm;
        float bv = b1[e * DFF + n];
        float rb = fmaxf(bv, 0.f);
        #pragma unroll
        for (int i = 0; i < 4; ++i) {
            int rbase = wr + i * 16 + ((lane >> 4) << 2);
            #pragma unroll
            for (int r = 0; r < 4; ++r) {
                float h = fmaxf(acc[i][j][r] + bv, 0.f) - rb;
                H[(size_t)(rstart + rbase + r) * DFF + n] = f2bf(h);
            }
        }
    }
}

// ---------------- GEMM 2: out[token] += score * (H @ W2) ----------------
// grid (DIM/128, MAXROWS/128), block 256. W2T layout [E][DIM][DFF] bf16.

__global__ __launch_bounds__(256, 2) void gemm2(
    const unsigned short* __restrict__ H, const unsigned short* __restrict__ w2t,
    const int* __restrict__ pair_token, const float* __restrict__ pair_score,
    const int* __restrict__ po, float* __restrict__ out) {
    __shared__ unsigned short As[128 * 32];
    __shared__ unsigned short Bs[128 * 32];
    __shared__ int ptok[128];
    __shared__ float pscr[128];

    int rstart = blockIdx.y * 128;
    int total = po[NEXP];
    if (rstart >= total) return;
    int e = 0;
    #pragma unroll
    for (int i = 0; i < NEXP - 1; ++i) if (rstart >= po[i + 1]) e = i + 1;

    int tid = threadIdx.x;
    if (tid < 128) {
        ptok[tid] = pair_token[rstart + tid];
        pscr[tid] = pair_score[rstart + tid];
    }
    __syncthreads();

    int wave = tid >> 6, lane = tid & 63;
    int wr = (wave >> 1) * 64, wc = (wave & 1) * 64;
    int lm = lane & 15, kq = lane >> 4;

    int rl = lane >> 2, q = lane & 3;
    int rA0 = wave * 32 + rl;
    int rA1 = rA0 + 16;
    int q0 = q ^ ((rA0 >> 1) & 3);
    int q1 = q ^ ((rA1 >> 1) & 3);

    const unsigned short* bbase =
        w2t + (size_t)e * DIM * DFF + (size_t)(blockIdx.x * 128) * DFF;
    const unsigned short* abase = H + (size_t)rstart * DFF;

    const unsigned short* gA0 = abase + (size_t)rA0 * DFF + q0 * 8;
    const unsigned short* gA1 = abase + (size_t)rA1 * DFF + q1 * 8;
    const unsigned short* gB0 = bbase + (size_t)rA0 * DFF + q0 * 8;
    const unsigned short* gB1 = bbase + (size_t)rA1 * DFF + q1 * 8;
    unsigned short* lA0 = &As[(wave * 32) * 32];
    unsigned short* lA1 = &As[(wave * 32 + 16) * 32];
    unsigned short* lB0 = &Bs[(wave * 32) * 32];
    unsigned short* lB1 = &Bs[(wave * 32 + 16) * 32];

    f32x4 acc[4][4];
    #pragma unroll
    for (int i = 0; i < 4; ++i)
        #pragma unroll
        for (int j = 0; j < 4; ++j) acc[i][j] = (f32x4){0.f, 0.f, 0.f, 0.f};

    for (int kt = 0; kt < DFF / 32; ++kt) {
        int k0 = kt * 32;
        if (kt) __syncthreads();
        __builtin_amdgcn_global_load_lds(AS1(gA0 + k0), AS3(lA0), 16, 0, 0);
        __builtin_amdgcn_global_load_lds(AS1(gA1 + k0), AS3(lA1), 16, 0, 0);
        __builtin_amdgcn_global_load_lds(AS1(gB0 + k0), AS3(lB0), 16, 0, 0);
        __builtin_amdgcn_global_load_lds(AS1(gB1 + k0), AS3(lB1), 16, 0, 0);
        __syncthreads();
        bf16x8 af[4], bfr[4];
        #pragma unroll
        for (int i = 0; i < 4; ++i) {
            int R = wr + i * 16 + lm;
            af[i] = *reinterpret_cast<const bf16x8*>(&As[R * 32 + ((kq ^ ((R >> 1) & 3)) << 3)]);
        }
        #pragma unroll
        for (int j = 0; j < 4; ++j) {
            int R = wc + j * 16 + lm;
            bfr[j] = *reinterpret_cast<const bf16x8*>(&Bs[R * 32 + ((kq ^ ((R >> 1) & 3)) << 3)]);
        }
        #pragma unroll
        for (int i = 0; i < 4; ++i)
            #pragma unroll
            for (int j = 0; j < 4; ++j)
                acc[i][j] = __builtin_amdgcn_mfma_f32_16x16x32_bf16(af[i], bfr[j], acc[i][j], 0, 0, 0);
    }

    int ctile = blockIdx.x * 128;
    #pragma unroll
    for (int j = 0; j < 4; ++j) {
        int n = ctile + wc + j * 16 + lm;
        #pragma unroll
        for (int i = 0; i < 4; ++i) {
            int rbase = wr + i * 16 + ((lane >> 4) << 2);
            #pragma unroll
            for (int r = 0; r < 4; ++r) {
                int rl2 = rbase + r;
                int tkn = ptok[rl2];
                if (tkn >= 0)
                    atomicAdd(out + (size_t)tkn * DIM + n, pscr[rl2] * acc[i][j][r]);
            }
        }
    }
}

// ---------------- launch ----------------

extern "C" void kernel_launch(void* const* d_in, const int* in_sizes, int n_in,
                              void* d_out, int out_size, void* d_ws, size_t ws_size,
                              hipStream_t stream) {
    const float* x   = (const float*)d_in[0];
    const float* w_g = (const float*)d_in[1];
    const float* b_g = (const float*)d_in[2];
    const float* W1  = (const float*)d_in[3];
    const float* b1  = (const float*)d_in[4];
    const float* W2  = (const float*)d_in[5];
    const float* b2  = (const float*)d_in[6];
    float* out = (float*)d_out;

    char* p = (char*)d_ws;
    auto alloc = [&](size_t bytes) {
        void* r = (void*)p;
        p += (bytes + 255) & ~(size_t)255;
        return r;
    };
    unsigned short* xb  = (unsigned short*)alloc((size_t)NTOK * DIM * 2);
    unsigned short* w1t = (unsigned short*)alloc((size_t)NEXP * DFF * DIM * 2);
    unsigned short* w2t = (unsigned short*)alloc((size_t)NEXP * DIM * DFF * 2);
    unsigned short* H   = (unsigned short*)alloc((size_t)MAXROWS * DFF * 2);
    int*   pair_token = (int*)alloc(MAXROWS * 4);
    float* pair_score = (float*)alloc(MAXROWS * 4);
    int*   tk_idx     = (int*)alloc(NTOK * 2 * 4);
    float* tk_score   = (float*)alloc(NTOK * 2 * 4);
    int*   counts     = (int*)alloc(NEXP * 4);
    int*   cursors    = (int*)alloc(NEXP * 4);
    int*   active     = (int*)alloc(2 * NEXP * 4);
    int*   po         = (int*)alloc((NEXP + 1) * 4);
    float* cbuf       = (float*)alloc(NEXP * DIM * 4);
    float* C2         = (float*)alloc(2 * DIM * 4);

    zero_init<<<(MAXROWS + 255) / 256, 256, 0, stream>>>(pair_token, counts, cursors, active, cbuf, b2);
    cvt_x<<<(NTOK * DIM + 255) / 256, 256, 0, stream>>>(x, xb);
    transpose_cvt<<<dim3(DFF / 32, DIM / 32, NEXP), dim3(32, 8), 0, stream>>>(W1, w1t, DIM, DFF);
    transpose_cvt<<<dim3(DIM / 32, DFF / 32, NEXP), dim3(32, 8), 0, stream>>>(W2, w2t, DFF, DIM);
    router<<<NTOK / 4, 256, 0, stream>>>(x, w_g, b_g, tk_idx, tk_score, counts, active);
    expert_const<<<dim3(DIM / 256, NEXP, DFF / 512), 256, 0, stream>>>(b1, W2, cbuf);
    prefix_off<<<1, 64, 0, stream>>>(counts, po);
    scatter_pairs<<<(2 * NTOK) / 256, 256, 0, stream>>>(tk_idx, tk_score, po, cursors, pair_token, pair_score);
    combine_C<<<(2 * DIM) / 256, 256, 0, stream>>>(active, cbuf, C2);
    init_out<<<(NTOK * DIM) / 256, 256, 0, stream>>>(tk_score, C2, out);
    gemm1<<<dim3(DFF / 128, MAXROWS / 128), 256, 0, stream>>>(xb, w1t, b1, pair_token, po, H);
    gemm2<<<dim3(DIM / 128, MAXROWS / 128), 256, 0, stream>>>(H, w2t, pair_token, pair_score, po, out);
}